// Round 5
// baseline (242.451 us; speedup 1.0000x reference)
//
#include <hip/hip_runtime.h>

// SPQR dequant-GEMV: y[b][m] = sum_n x[b][n] * Wd[m][n] + CSR outlier correction
// M=N=8192, beta1=beta2=16, B(=b*l)=10, 32 nnz/row.
// R5: cross-chunk W double-buffer with FLAT named registers, 2 cols/thread,
//     occupancy 4 waves/SIMD, and vmcnt-safe issue order per chunk:
//     [x loads for c] -> [W prefetch c+1] -> dequant(c) -> FMAs(c).
//     (x waits use counted vmcnt; prefetch stays in flight through compute.)

constexpr int M_DIM = 8192;
constexpr int N_DIM = 8192;
constexpr int TN    = 512;          // N / 16
constexpr int BQ    = 10;           // batch (b*l)
constexpr int RB    = 4;            // rows per block
constexpr int NTHREADS = 256;
constexpr int CC    = NTHREADS * 2; // 512 columns per chunk (2 cols/thread)
constexpr int NCHUNK = N_DIM / CC;  // 16
constexpr int NOUT  = RB * BQ;      // 40 partial outputs per block

typedef float v2f __attribute__((ext_vector_type(2)));
typedef int   v2i __attribute__((ext_vector_type(2)));

__global__ __launch_bounds__(NTHREADS, 4)
void spqr_fused(const float* __restrict__ x,
                const int*   __restrict__ W,
                const int*   __restrict__ Ws,
                const int*   __restrict__ Wz,
                const float* __restrict__ Wss,
                const float* __restrict__ Wsz,
                const float* __restrict__ Wzs,
                const float* __restrict__ Wzz,
                const int*   __restrict__ row_offsets,
                const int*   __restrict__ col_ids,
                const float* __restrict__ values,
                float*       __restrict__ y)
{
    const int t  = threadIdx.x;
    const int m0 = blockIdx.x * RB;
    const int ti = m0 >> 4;                 // all 4 rows in the same 16-row tile
    const int tc = t * 2;

    float acc[RB][BQ];
    #pragma unroll
    for (int r = 0; r < RB; ++r)
        #pragma unroll
        for (int b = 0; b < BQ; ++b)
            acc[r][b] = 0.f;

    // flat double-buffer registers (no structs -> no scratch risk)
    v2i wcA[RB]; int sA[RB], zA[RB]; float ssA, szA, zsA, zzA;
    v2i wcB[RB]; int sB[RB], zB[RB]; float ssB, szB, zsB, zzB;

// issue chunk-(c) W/scale/zero/tile loads into suffix-SUF registers
#define LOADW(SUF, c) do {                                                    \
    const int n0_ = (c) * CC + tc;                                            \
    const int g_  = n0_ >> 4;                                                 \
    const int ix_ = ti * TN + g_;                                             \
    _Pragma("unroll")                                                         \
    for (int r_ = 0; r_ < RB; ++r_) {                                         \
        const int m_ = m0 + r_;                                               \
        wc##SUF[r_] = *reinterpret_cast<const v2i*>(W + (size_t)m_ * N_DIM + n0_); \
        s##SUF[r_]  = Ws[m_ * TN + g_];                                       \
        z##SUF[r_]  = Wz[m_ * TN + g_];                                       \
    }                                                                         \
    ss##SUF = Wss[ix_]; sz##SUF = Wsz[ix_];                                   \
    zs##SUF = Wzs[ix_]; zz##SUF = Wzz[ix_];                                   \
} while (0)

// process chunk c using CUR-suffix registers; prefetch c+1 into NXT-suffix.
// order: x loads (c) FIRST, then prefetch, then dequant+FMA.
#define BODY(CUR, NXT, c) do {                                                \
    const int n0_ = (c) * CC + tc;                                            \
    v2f xv_[BQ];                                                              \
    _Pragma("unroll")                                                         \
    for (int b_ = 0; b_ < BQ; ++b_)                                           \
        xv_[b_] = *reinterpret_cast<const v2f*>(x + b_ * N_DIM + n0_);        \
    if ((c) + 1 < NCHUNK) LOADW(NXT, (c) + 1);                                \
    float w_[RB][2];                                                          \
    _Pragma("unroll")                                                         \
    for (int r_ = 0; r_ < RB; ++r_) {                                         \
        const float s_ = ((float)s##CUR[r_] - sz##CUR) * ss##CUR;             \
        const float z_ = ((float)z##CUR[r_] - zz##CUR) * zs##CUR;             \
        w_[r_][0] = ((float)wc##CUR[r_].x - z_) * s_;                         \
        w_[r_][1] = ((float)wc##CUR[r_].y - z_) * s_;                         \
    }                                                                         \
    _Pragma("unroll")                                                         \
    for (int b_ = 0; b_ < BQ; ++b_) {                                         \
        const v2f xb_ = xv_[b_];                                              \
        _Pragma("unroll")                                                     \
        for (int r_ = 0; r_ < RB; ++r_)                                       \
            acc[r_][b_] = fmaf(w_[r_][1], xb_.y,                              \
                          fmaf(w_[r_][0], xb_.x, acc[r_][b_]));               \
    }                                                                         \
} while (0)

    LOADW(A, 0);
    for (int c = 0; c < NCHUNK; c += 2) {
        BODY(A, B, c);
        BODY(B, A, c + 1);
    }

#undef BODY
#undef LOADW

    // ---- fused CSR outlier correction: 32 lanes per row, 4 rows = 128 threads ----
    __shared__ float lsp[RB][BQ];
    if (t < RB * 32) {
        const int r = t >> 5;
        const int j = t & 31;
        const int m = m0 + r;
        const int base = row_offsets[m];
        const int cnt  = row_offsets[m + 1] - base;
        float c[BQ];
        #pragma unroll
        for (int b = 0; b < BQ; ++b) c[b] = 0.f;
        for (int jj = j; jj < cnt; jj += 32) {
            const int   col = col_ids[base + jj];
            const float v   = values[base + jj];
            #pragma unroll
            for (int b = 0; b < BQ; ++b)
                c[b] = fmaf(v, x[b * N_DIM + col], c[b]);
        }
        #pragma unroll
        for (int b = 0; b < BQ; ++b) {
            float v = c[b];
            for (int off = 16; off > 0; off >>= 1)
                v += __shfl_xor(v, off, 32);
            c[b] = v;
        }
        if (j == 0) {
            #pragma unroll
            for (int b = 0; b < BQ; ++b)
                lsp[r][b] = c[b];
        }
    }

    // ---- dense reduction: 2-step quad shuffle, then LDS tree ----
    #pragma unroll
    for (int r = 0; r < RB; ++r)
        #pragma unroll
        for (int b = 0; b < BQ; ++b) {
            float v = acc[r][b];
            v += __shfl_xor(v, 1, 64);
            v += __shfl_xor(v, 2, 64);
            acc[r][b] = v;
        }

    __shared__ float lred[64][NOUT + 1];    // 64 quads x 40 outs (+pad)
    if ((t & 3) == 0) {
        const int q = t >> 2;
        #pragma unroll
        for (int r = 0; r < RB; ++r)
            #pragma unroll
            for (int b = 0; b < BQ; ++b)
                lred[q][r * BQ + b] = acc[r][b];
    }
    __shared__ float l2[NOUT][2];
    __syncthreads();

    if (t < 2 * NOUT) {                     // 80 threads: each sums 32 quads
        const int out = t % NOUT;
        const int h   = t / NOUT;
        float v = 0.f;
        #pragma unroll
        for (int q = 0; q < 32; ++q)
            v += lred[h * 32 + q][out];
        l2[out][h] = v;
    }
    __syncthreads();

    if (t < NOUT) {                         // 40 threads: final combine + write
        const int r = t / BQ;
        const int b = t % BQ;
        y[b * M_DIM + (m0 + r)] = l2[t][0] + l2[t][1] + lsp[r][b];
    }
}

extern "C" void kernel_launch(void* const* d_in, const int* in_sizes, int n_in,
                              void* d_out, int out_size, void* d_ws, size_t ws_size,
                              hipStream_t stream)
{
    const float* x    = (const float*)d_in[0];
    const int*   W    = (const int*)  d_in[1];
    const int*   Ws   = (const int*)  d_in[2];
    const int*   Wz   = (const int*)  d_in[3];
    const float* Wss  = (const float*)d_in[4];
    const float* Wsz  = (const float*)d_in[5];
    const float* Wzs  = (const float*)d_in[6];
    const float* Wzz  = (const float*)d_in[7];
    const int*   roff = (const int*)  d_in[8];
    const int*   cids = (const int*)  d_in[9];
    const float* vals = (const float*)d_in[10];
    float* yout = (float*)d_out;

    dim3 grid(M_DIM / RB);                  // 2048 blocks
    dim3 block(NTHREADS);
    spqr_fused<<<grid, block, 0, stream>>>(x, W, Ws, Wz, Wss, Wsz, Wzs, Wzz,
                                           roff, cids, vals, yout);
}

// Round 6
// 91.936 us; speedup vs baseline: 2.6372x; 2.6372x over previous
//
#include <hip/hip_runtime.h>

// SPQR dequant-GEMV: y[b][m] = sum_n x[b][n] * Wd[m][n] + CSR outlier correction
// M=N=8192, beta1=beta2=16, B(=b*l)=10, 32 nnz/row.
// R6: W double-buffered in LDS via global_load_lds (zero VGPR prefetch cost),
//     2-phase pipeline with counted vmcnt + raw s_barrier (no __syncthreads
//     drain in the main loop). Registers hold only acc + current x + temps.

constexpr int M_DIM = 8192;
constexpr int N_DIM = 8192;
constexpr int TN    = 512;          // N / 16
constexpr int BQ    = 10;           // batch (b*l)
constexpr int RB    = 4;            // rows per block (= waves per block)
constexpr int NTHREADS = 256;
constexpr int NC    = NTHREADS * 4; // 1024 columns per chunk (4 cols/thread)
constexpr int NCHUNK = N_DIM / NC;  // 8
constexpr int NOUT  = RB * BQ;      // 40 partial outputs per block
constexpr int PH_INTS = RB * NC;    // 4096 ints = 16KB per phase

#define AS1C(p) ((const __attribute__((address_space(1))) void*)(p))
#define AS3(p)  ((__attribute__((address_space(3))) void*)(p))

__global__ __launch_bounds__(NTHREADS, 4)
void spqr_fused(const float* __restrict__ x,
                const int*   __restrict__ W,
                const int*   __restrict__ Ws,
                const int*   __restrict__ Wz,
                const float* __restrict__ Wss,
                const float* __restrict__ Wsz,
                const float* __restrict__ Wzs,
                const float* __restrict__ Wzz,
                const int*   __restrict__ row_offsets,
                const int*   __restrict__ col_ids,
                const float* __restrict__ values,
                float*       __restrict__ y)
{
    __shared__ __align__(16) int smem[2 * PH_INTS];   // 32 KB: W double buffer

    const int t    = threadIdx.x;
    const int lane = t & 63;
    const int wv   = t >> 6;               // wave id == staged row id
    const int m0   = blockIdx.x * RB;
    const int ti   = m0 >> 4;              // all RB rows in one 16-row tile

    float acc[RB][BQ];
    #pragma unroll
    for (int r = 0; r < RB; ++r)
        #pragma unroll
        for (int b = 0; b < BQ; ++b)
            acc[r][b] = 0.f;

    // wave wv stages row (m0+wv): 4KB row = 4 x (64 lanes x 16B)
    const int* gRowBase = W + (size_t)(m0 + wv) * N_DIM + lane * 4;
    #define STAGE(c) do {                                                     \
        const int* gsrc_ = gRowBase + (c) * NC;                               \
        int* ldst_ = &smem[((c) & 1) * PH_INTS + wv * NC];                    \
        _Pragma("unroll")                                                     \
        for (int i_ = 0; i_ < 4; ++i_)                                        \
            __builtin_amdgcn_global_load_lds(AS1C(gsrc_ + i_ * 256),          \
                                             AS3(ldst_ + i_ * 256), 16, 0, 0);\
    } while (0)

    STAGE(0);

    for (int c = 0; c < NCHUNK; ++c) {
        const int n0 = c * NC + t * 4;     // this thread's 4 columns
        const int g  = n0 >> 4;
        const int ix = ti * TN + g;

        // ---- issue all register loads for chunk c FIRST (older than stage) ----
        float4 xv[BQ];
        #pragma unroll
        for (int b = 0; b < BQ; ++b)
            xv[b] = *reinterpret_cast<const float4*>(x + b * N_DIM + n0);
        int sreg[RB], zreg[RB];
        #pragma unroll
        for (int r = 0; r < RB; ++r) {
            sreg[r] = Ws[(m0 + r) * TN + g];
            zreg[r] = Wz[(m0 + r) * TN + g];
        }
        const float wss = Wss[ix];
        const float wsz = Wsz[ix];
        const float wzs = Wzs[ix];
        const float wzz = Wzz[ix];

        __builtin_amdgcn_sched_barrier(0);  // keep stage AFTER the reg loads

        if (c + 1 < NCHUNK) {
            STAGE(c + 1);
            __builtin_amdgcn_sched_barrier(0);
            // wait: everything except the 4 just-issued stage ops.
            // guarantees buf[c&1] (staged last iter) is complete.
            asm volatile("s_waitcnt vmcnt(4)" ::: "memory");
        } else {
            asm volatile("s_waitcnt vmcnt(0)" ::: "memory");
        }
        __builtin_amdgcn_s_barrier();       // raw barrier: no vmcnt(0) drain

        // ---- compute chunk c from LDS buf[c&1] ----
        const int* buf = &smem[(c & 1) * PH_INTS];
        #pragma unroll
        for (int r = 0; r < RB; ++r) {
            const int4 wc = *reinterpret_cast<const int4*>(&buf[r * NC + t * 4]);
            const float s = ((float)sreg[r] - wsz) * wss;
            const float z = ((float)zreg[r] - wzz) * wzs;
            const float w0 = ((float)wc.x - z) * s;
            const float w1 = ((float)wc.y - z) * s;
            const float w2 = ((float)wc.z - z) * s;
            const float w3 = ((float)wc.w - z) * s;
            #pragma unroll
            for (int b = 0; b < BQ; ++b) {
                float a = acc[r][b];
                a = fmaf(w0, xv[b].x, a);
                a = fmaf(w1, xv[b].y, a);
                a = fmaf(w2, xv[b].z, a);
                a = fmaf(w3, xv[b].w, a);
                acc[r][b] = a;
            }
        }
        __builtin_amdgcn_s_barrier();       // don't let fast waves re-stage over
    }                                       // a buffer slower waves still read
    #undef STAGE

    // ---- epilogue LDS overlays buf0 (dead: last chunk used buf1) ----
    float (*lred)[NOUT + 1] = (float (*)[NOUT + 1])smem;          // 64 x 41
    float (*lsp)[BQ]        = (float (*)[BQ])(smem + 64 * (NOUT + 1));
    float (*l2v)[2]         = (float (*)[2])(smem + 64 * (NOUT + 1) + NOUT);

    // ---- fused CSR outlier correction: 32 lanes per row, 4 rows = 128 threads ----
    if (t < RB * 32) {
        const int r = t >> 5;
        const int j = t & 31;
        const int m = m0 + r;
        const int base = row_offsets[m];
        const int cnt  = row_offsets[m + 1] - base;
        float cacc[BQ];
        #pragma unroll
        for (int b = 0; b < BQ; ++b) cacc[b] = 0.f;
        for (int jj = j; jj < cnt; jj += 32) {
            const int   col = col_ids[base + jj];
            const float v   = values[base + jj];
            #pragma unroll
            for (int b = 0; b < BQ; ++b)
                cacc[b] = fmaf(v, x[b * N_DIM + col], cacc[b]);
        }
        #pragma unroll
        for (int b = 0; b < BQ; ++b) {
            float v = cacc[b];
            for (int off = 16; off > 0; off >>= 1)
                v += __shfl_xor(v, off, 32);
            cacc[b] = v;
        }
        if (j == 0) {
            #pragma unroll
            for (int b = 0; b < BQ; ++b)
                lsp[r][b] = cacc[b];
        }
    }

    // ---- dense reduction: 2-step quad shuffle, then LDS tree ----
    #pragma unroll
    for (int r = 0; r < RB; ++r)
        #pragma unroll
        for (int b = 0; b < BQ; ++b) {
            float v = acc[r][b];
            v += __shfl_xor(v, 1, 64);
            v += __shfl_xor(v, 2, 64);
            acc[r][b] = v;
        }

    if ((t & 3) == 0) {
        const int q = t >> 2;
        #pragma unroll
        for (int r = 0; r < RB; ++r)
            #pragma unroll
            for (int b = 0; b < BQ; ++b)
                lred[q][r * BQ + b] = acc[r][b];
    }
    __syncthreads();

    if (t < 2 * NOUT) {                     // 80 threads: each sums 32 quads
        const int out = t % NOUT;
        const int h   = t / NOUT;
        float v = 0.f;
        #pragma unroll
        for (int q = 0; q < 32; ++q)
            v += lred[h * 32 + q][out];
        l2v[out][h] = v;
    }
    __syncthreads();

    if (t < NOUT) {                         // 40 threads: final combine + write
        const int r = t / BQ;
        const int b = t % BQ;
        y[b * M_DIM + (m0 + r)] = l2v[t][0] + l2v[t][1] + lsp[r][b];
    }
}

extern "C" void kernel_launch(void* const* d_in, const int* in_sizes, int n_in,
                              void* d_out, int out_size, void* d_ws, size_t ws_size,
                              hipStream_t stream)
{
    const float* x    = (const float*)d_in[0];
    const int*   W    = (const int*)  d_in[1];
    const int*   Ws   = (const int*)  d_in[2];
    const int*   Wz   = (const int*)  d_in[3];
    const float* Wss  = (const float*)d_in[4];
    const float* Wsz  = (const float*)d_in[5];
    const float* Wzs  = (const float*)d_in[6];
    const float* Wzz  = (const float*)d_in[7];
    const int*   roff = (const int*)  d_in[8];
    const int*   cids = (const int*)  d_in[9];
    const float* vals = (const float*)d_in[10];
    float* yout = (float*)d_out;

    dim3 grid(M_DIM / RB);                  // 2048 blocks
    dim3 block(NTHREADS);
    spqr_fused<<<grid, block, 0, stream>>>(x, W, Ws, Wz, Wss, Wsz, Wzs, Wzz,
                                           roff, cids, vals, yout);
}

// Round 7
// 79.168 us; speedup vs baseline: 3.0625x; 1.1613x over previous
//
#include <hip/hip_runtime.h>

// SPQR dequant-GEMV via MFMA: y = x @ Wd^T + CSR, M=N=8192, B=10, beta=16x16.
// R7: matrix-core reformulation. Wave = one 16-row W tile; K split 16 ways;
//     A-frags (x, bf16) + dequantized s/z staged in LDS once per block;
//     main loop = W-code stream (2 dwordx4, 3-deep reg prefetch) + dequant + MFMA.
//     Partials to d_ws; reduce+CSR kernel finishes. No atomics.

constexpr int M_DIM = 8192;
constexpr int N_DIM = 8192;
constexpr int TN    = 512;              // N/16 scale groups per row
constexpr int BQ    = 10;               // batch (b*l)
constexpr int KSPLIT = 16;
constexpr int KRANGE = N_DIM / KSPLIT;  // 512
constexpr int KITERS = KRANGE / 32;     // 16 MFMA k-steps per wave
constexpr int RPB    = 64;              // rows per block (4 waves x 16)
constexpr int GPB    = KRANGE / 16;     // 32 scale groups per block k-range

typedef float  f32x4  __attribute__((ext_vector_type(4)));
typedef float  f32x2  __attribute__((ext_vector_type(2)));
typedef int    i32x4  __attribute__((ext_vector_type(4)));
typedef short  bf16x8 __attribute__((ext_vector_type(8)));

__device__ inline ushort f2bf(float f) {           // f32 -> bf16 (RNE)
    unsigned u = __float_as_uint(f);
    u += 0x7fffu + ((u >> 16) & 1u);
    return (ushort)(u >> 16);
}

__global__ __launch_bounds__(256, 4)
void spqr_mfma(const float* __restrict__ x,
               const int*   __restrict__ W,
               const int*   __restrict__ Ws,
               const int*   __restrict__ Wz,
               const float* __restrict__ Wss,
               const float* __restrict__ Wsz,
               const float* __restrict__ Wzs,
               const float* __restrict__ Wzz,
               float*       __restrict__ pws)
{
    __shared__ int   ldsA[KITERS * 64 * 4];        // 16KB: bf16 A-frags per k-iter/lane
    __shared__ f32x2 ldsSZ[RPB * 33];              // 16.9KB: (s,z) f32 pairs, padded

    const int t   = threadIdx.x;
    const int m0b = blockIdx.x * RPB;
    const int ks  = blockIdx.y;
    const int k0  = ks * KRANGE;
    const int g0  = k0 >> 4;

    // ---- stage A-fragments: lane l of k-iter kk holds x[b=l&15][k0+kk*32+(l>>4)*8 ..+7]
    for (int idx = t; idx < KITERS * 64; idx += 256) {
        const int kk = idx >> 6, l = idx & 63;
        const int b = l & 15, koff = (kk << 5) + ((l >> 4) << 3);
        int out[4] = {0, 0, 0, 0};
        if (b < BQ) {
            const float* xp = x + b * N_DIM + k0 + koff;
            f32x4 lo = *reinterpret_cast<const f32x4*>(xp);
            f32x4 hi = *reinterpret_cast<const f32x4*>(xp + 4);
            out[0] = f2bf(lo.x) | ((unsigned)f2bf(lo.y) << 16);
            out[1] = f2bf(lo.z) | ((unsigned)f2bf(lo.w) << 16);
            out[2] = f2bf(hi.x) | ((unsigned)f2bf(hi.y) << 16);
            out[3] = f2bf(hi.z) | ((unsigned)f2bf(hi.w) << 16);
        }
        *reinterpret_cast<i32x4*>(&ldsA[idx * 4]) = *reinterpret_cast<i32x4*>(out);
    }

    // ---- stage dequantized first-order (s,z) as f32 pairs
    for (int idx = t; idx < RPB * GPB; idx += 256) {
        const int rl = idx >> 5;                   // local row 0..63
        const int gl = idx & 31;                   // local group 0..31
        const int m = m0b + rl, g = g0 + gl;
        const int tix = (m >> 4) * TN + g;
        const float s = ((float)Ws[m * TN + g] - Wsz[tix]) * Wss[tix];
        const float z = ((float)Wz[m * TN + g] - Wzz[tix]) * Wzs[tix];
        ldsSZ[rl * 33 + gl] = (f32x2){s, z};
    }
    __syncthreads();

    // ---- main loop: stream W codes, dequant, MFMA ----
    const int wv = t >> 6, l = t & 63;
    const int lrow = l & 15;                       // tile row (W row offset / C col)
    const int lk   = l >> 4;                       // k-sub 0..3
    const int m0   = m0b + (wv << 4);
    const int* wp  = W + (size_t)(m0 + lrow) * N_DIM + k0 + (lk << 3);
    const int szrow = (wv << 4) + lrow;
    const int szk   = lk >> 1;                     // group offset within k-iter

    f32x4 acc = {0.f, 0.f, 0.f, 0.f};
    i32x4 cbufL[4], cbufH[4];                      // 3-deep rotating prefetch

    #pragma unroll
    for (int p = 0; p < 3; ++p) {
        cbufL[p] = *reinterpret_cast<const i32x4*>(wp + p * 32);
        cbufH[p] = *reinterpret_cast<const i32x4*>(wp + p * 32 + 4);
    }

    #pragma unroll
    for (int kk = 0; kk < KITERS; ++kk) {
        if (kk + 3 < KITERS) {
            cbufL[(kk + 3) & 3] = *reinterpret_cast<const i32x4*>(wp + (kk + 3) * 32);
            cbufH[(kk + 3) & 3] = *reinterpret_cast<const i32x4*>(wp + (kk + 3) * 32 + 4);
        }
        const i32x4 a4 = *reinterpret_cast<const i32x4*>(&ldsA[(kk * 64 + l) * 4]);
        const f32x2 sz = ldsSZ[szrow * 33 + kk * 2 + szk];
        const float s  = sz.x;
        const float nzs = -sz.y * sz.x;            // w = code*s + nzs
        const i32x4 cl = cbufL[kk & 3], ch = cbufH[kk & 3];
        const int c[8] = {cl.x, cl.y, cl.z, cl.w, ch.x, ch.y, ch.z, ch.w};
        int bw[4];
        #pragma unroll
        for (int d = 0; d < 4; ++d) {
            const float w0 = fmaf((float)c[2 * d],     s, nzs);
            const float w1 = fmaf((float)c[2 * d + 1], s, nzs);
            bw[d] = f2bf(w0) | ((unsigned)f2bf(w1) << 16);
        }
        const bf16x8 af = __builtin_bit_cast(bf16x8, a4);
        const bf16x8 bf = __builtin_bit_cast(bf16x8, *reinterpret_cast<i32x4*>(bw));
        acc = __builtin_amdgcn_mfma_f32_16x16x32_bf16(af, bf, acc, 0, 0, 0);
    }

    // ---- store partials: C[row=b=(l>>4)*4+j][col=lrow] -> pws[ks][b][m0+lrow]
    float* pb = pws + (size_t)ks * (BQ * N_DIM) + (m0 + lrow);
    #pragma unroll
    for (int j = 0; j < 4; ++j) {
        const int b = (lk << 2) + j;
        if (b < BQ) pb[(size_t)b * N_DIM] = acc[j];
    }
}

__global__ __launch_bounds__(256, 4)
void spqr_reduce(const float* __restrict__ x,
                 const int*   __restrict__ row_offsets,
                 const int*   __restrict__ col_ids,
                 const float* __restrict__ values,
                 const float* __restrict__ pws,
                 float*       __restrict__ y)
{
    __shared__ float lsp[8][BQ];
    const int t  = threadIdx.x;
    const int m0 = blockIdx.x * 8;

    // CSR: 32 lanes per row, 8 rows
    {
        const int r = t >> 5, j = t & 31;
        const int m = m0 + r;
        const int base = row_offsets[m];
        const int cnt  = row_offsets[m + 1] - base;
        float c[BQ];
        #pragma unroll
        for (int b = 0; b < BQ; ++b) c[b] = 0.f;
        for (int jj = j; jj < cnt; jj += 32) {
            const int   col = col_ids[base + jj];
            const float v   = values[base + jj];
            #pragma unroll
            for (int b = 0; b < BQ; ++b)
                c[b] = fmaf(v, x[b * N_DIM + col], c[b]);
        }
        #pragma unroll
        for (int b = 0; b < BQ; ++b) {
            float v = c[b];
            for (int off = 16; off > 0; off >>= 1)
                v += __shfl_xor(v, off, 32);
            c[b] = v;
        }
        if (j == 0) {
            #pragma unroll
            for (int b = 0; b < BQ; ++b) lsp[r][b] = c[b];
        }
    }
    __syncthreads();

    if (t < 8 * BQ) {
        const int ml = t / BQ, b = t % BQ;
        const int m = m0 + ml;
        float v = lsp[ml][b];
        const float* pp = pws + (size_t)b * N_DIM + m;
        #pragma unroll
        for (int ksp = 0; ksp < KSPLIT; ++ksp)
            v += pp[(size_t)ksp * (BQ * N_DIM)];
        y[(size_t)b * M_DIM + m] = v;
    }
}

extern "C" void kernel_launch(void* const* d_in, const int* in_sizes, int n_in,
                              void* d_out, int out_size, void* d_ws, size_t ws_size,
                              hipStream_t stream)
{
    const float* x    = (const float*)d_in[0];
    const int*   W    = (const int*)  d_in[1];
    const int*   Ws   = (const int*)  d_in[2];
    const int*   Wz   = (const int*)  d_in[3];
    const float* Wss  = (const float*)d_in[4];
    const float* Wsz  = (const float*)d_in[5];
    const float* Wzs  = (const float*)d_in[6];
    const float* Wzz  = (const float*)d_in[7];
    const int*   roff = (const int*)  d_in[8];
    const int*   cids = (const int*)  d_in[9];
    const float* vals = (const float*)d_in[10];
    float* yout = (float*)d_out;
    float* pws  = (float*)d_ws;                   // 16 x 10 x 8192 f32 = 5.24 MB

    dim3 grid1(M_DIM / RPB, KSPLIT);              // 128 x 16 = 2048 blocks
    spqr_mfma<<<grid1, dim3(256), 0, stream>>>(x, W, Ws, Wz, Wss, Wsz, Wzs, Wzz, pws);

    dim3 grid2(M_DIM / 8);                        // 1024 blocks
    spqr_reduce<<<grid2, dim3(256), 0, stream>>>(x, roff, cids, vals, pws, yout);
}